// Round 7
// baseline (566.185 us; speedup 1.0000x reference)
//
#include <hip/hip_runtime.h>
#include <math.h>

#define CI   700
#define TIN  300
#define DD   25
#define TOUT 276
#define BB   64
#define OINH 128
#define OEXC 256

#define TROWS 312          // padded t-rows in xT
#define IPAD  704          // channels padded to 22*32

typedef __attribute__((ext_vector_type(8))) short short8;
typedef __attribute__((ext_vector_type(4))) float f32x4;
typedef __attribute__((ext_vector_type(8))) unsigned short ushort8v;

static __device__ __forceinline__ unsigned short f2bf(float f) {
    unsigned int u = __float_as_uint(f);
    unsigned int r = (u + 0x7FFFu + ((u >> 16) & 1u)) >> 16;   // RNE
    return (unsigned short)r;
}
static __device__ __forceinline__ float bf2f(unsigned short h) {
    return __uint_as_float(((unsigned int)h) << 16);
}

static __device__ __forceinline__ void gload_lds16(const void* g, void* l) {
    __builtin_amdgcn_global_load_lds(
        (const __attribute__((address_space(1))) unsigned int*)g,
        (__attribute__((address_space(3))) unsigned int*)l, 16, 0, 0);
}

// ---------------------------------------------------------------------------
// Fallback inh path: fp32 DCLS kernel, layout kt[(i*25+d)*OINH + o]
// ---------------------------------------------------------------------------
__global__ void build_kt(const float* __restrict__ W, const float* __restrict__ P,
                         const float* __restrict__ SIG, float* __restrict__ kt, int O) {
    int n = blockIdx.x * 256 + threadIdx.x;
    if (n >= O * CI) return;
    int o = n % O;
    int i = n / O;
    float w   = fabsf(W[o * CI + i]);
    float p   = fminf(fmaxf(P[o * CI + i], -12.f), 12.f) + 12.f;
    float sig = fabsf(SIG[o * CI + i]) + 0.27f;
    float inv = 1.f / sig;
    float g[DD];
    float sum = 0.f;
#pragma unroll
    for (int d = 0; d < DD; ++d) {
        float e = ((float)d - p) * inv;
        g[d] = expf(-0.5f * e * e);
        sum += g[d];
    }
    float sc = w / (sum + 1e-7f);
#pragma unroll
    for (int d = 0; d < DD; ++d)
        kt[(i * DD + d) * O + o] = g[d] * sc;
}

// ---------------------------------------------------------------------------
// Exc path: bf16 DCLS kernel (hi only), layout kb2[d][o][ipad]
// ---------------------------------------------------------------------------
__global__ void kexc_build(const float* __restrict__ W, const float* __restrict__ P,
                           const float* __restrict__ SIG, unsigned short* __restrict__ kb2) {
    int n = blockIdx.x * 256 + threadIdx.x;           // n = o*IPAD + ip
    if (n >= OEXC * IPAD) return;
    int o = n / IPAD, ip = n % IPAD;
    if (ip >= CI) {
#pragma unroll
        for (int d = 0; d < DD; ++d)
            kb2[((size_t)d * OEXC + o) * IPAD + ip] = 0;
        return;
    }
    float w   = fabsf(W[o * CI + ip]);
    float p   = fminf(fmaxf(P[o * CI + ip], -12.f), 12.f) + 12.f;
    float sig = fabsf(SIG[o * CI + ip]) + 0.27f;
    float inv = 1.f / sig;
    float g[DD];
    float sum = 0.f;
#pragma unroll
    for (int d = 0; d < DD; ++d) {
        float e = ((float)d - p) * inv;
        g[d] = expf(-0.5f * e * e);
        sum += g[d];
    }
    float sc = w / (sum + 1e-7f);
#pragma unroll
    for (int d = 0; d < DD; ++d)
        kb2[((size_t)d * OEXC + o) * IPAD + ip] = f2bf(g[d] * sc);
}

// ---------------------------------------------------------------------------
// Inh path (fast): split bf16 hi/lo DCLS kernel, layout [d][o][ipad] x2
// ---------------------------------------------------------------------------
__global__ void kinh_build(const float* __restrict__ W, const float* __restrict__ P,
                           const float* __restrict__ SIG,
                           unsigned short* __restrict__ kbh, unsigned short* __restrict__ kbl) {
    int n = blockIdx.x * 256 + threadIdx.x;           // n = o*IPAD + ip
    if (n >= OINH * IPAD) return;
    int o = n / IPAD, ip = n % IPAD;
    if (ip >= CI) {
#pragma unroll
        for (int d = 0; d < DD; ++d) {
            kbh[((size_t)d * OINH + o) * IPAD + ip] = 0;
            kbl[((size_t)d * OINH + o) * IPAD + ip] = 0;
        }
        return;
    }
    float w   = fabsf(W[o * CI + ip]);
    float p   = fminf(fmaxf(P[o * CI + ip], -12.f), 12.f) + 12.f;
    float sig = fabsf(SIG[o * CI + ip]) + 0.27f;
    float inv = 1.f / sig;
    float g[DD];
    float sum = 0.f;
#pragma unroll
    for (int d = 0; d < DD; ++d) {
        float e = ((float)d - p) * inv;
        g[d] = expf(-0.5f * e * e);
        sum += g[d];
    }
    float sc = w / (sum + 1e-7f);
#pragma unroll
    for (int d = 0; d < DD; ++d) {
        float v = g[d] * sc;
        unsigned short h = f2bf(v);
        kbh[((size_t)d * OINH + o) * IPAD + ip] = h;
        kbl[((size_t)d * OINH + o) * IPAD + ip] = f2bf(v - bf2f(h));
    }
}

// ---------------------------------------------------------------------------
// xT[b][t][ipad] bf16 hi (+optional lo) = x[b][i][t]. LDS transpose, 64x64.
// grid (5 tchunks, 11 ichunks, 64 b).
// ---------------------------------------------------------------------------
__global__ __launch_bounds__(256)
void xt_kernel(const float* __restrict__ x, unsigned short* __restrict__ xTh,
               unsigned short* __restrict__ xTl) {
    __shared__ float tile[64][65];
    const int tid = threadIdx.x;
    const int t0 = blockIdx.x * 64, i0 = blockIdx.y * 64, b = blockIdx.z;
#pragma unroll
    for (int s = 0; s < 16; ++s) {
        int f = s * 256 + tid;
        int tt = f & 63, ii = f >> 6;
        float v = 0.f;
        if (t0 + tt < TIN && i0 + ii < CI)
            v = x[((size_t)b * CI + i0 + ii) * TIN + t0 + tt];
        tile[tt][ii] = v;
    }
    __syncthreads();
#pragma unroll
    for (int s = 0; s < 2; ++s) {
        int f = s * 256 + tid;
        int tt = f >> 3, g = f & 7;
        if (t0 + tt < TROWS) {
            ushort8v vh, vl;
#pragma unroll
            for (int e = 0; e < 8; ++e) {
                float v = tile[tt][g * 8 + e];
                unsigned short h = f2bf(v);
                vh[e] = h;
                vl[e] = f2bf(v - bf2f(h));
            }
            size_t off = ((size_t)b * TROWS + t0 + tt) * IPAD + i0 + g * 8;
            *(ushort8v*)(xTh + off) = vh;
            if (xTl) *(ushort8v*)(xTl + off) = vl;
        }
    }
}

// ---------------------------------------------------------------------------
// wt[c*256 + o] = -|w[o*128 + c]|
// ---------------------------------------------------------------------------
__global__ void wt_kernel(const float* __restrict__ w, float* __restrict__ wt) {
    int n = blockIdx.x * 256 + threadIdx.x;
    if (n >= OINH * OEXC) return;
    int o = n % OEXC, c = n / OEXC;
    wt[c * OEXC + o] = -fabsf(w[o * OINH + c]);
}

// ===========================================================================
// FUSED conv v3: 3-deep k pipeline with counted vmcnt; inh waves o-split
// (no per-d barrier). grid (6, 4, 64), 128 thr = 2 waves.
//   blockIdx.x: tt = x%3 (t0 = tt*96), ksp = x/3 (chunks [11ksp, 11ksp+11))
//   blockIdx.y: 0,1 = exc (o0 = y*128 + wave*64); 2,3 = inh (o0 = (y-2)*64,
//               wave owns 32 o)
// LDS: exc xs(8KB)+ks 3bufs(24KB)=32KB; inh xsh+xsl(16KB)+k 3bufs(24KB)=40KB.
// Swizzle identical to round 6 (proven 0-conflict).
// ===========================================================================
__global__ __launch_bounds__(128)
void conv_fused_v3(const unsigned short* __restrict__ xTh, const unsigned short* __restrict__ xTl,
                   const unsigned short* __restrict__ kb2,
                   const unsigned short* __restrict__ kbh, const unsigned short* __restrict__ kbl,
                   float* __restrict__ pexc0, float* __restrict__ pexc1,
                   float* __restrict__ pinh0, float* __restrict__ pinh1) {
    __shared__ unsigned short lds[20480];          // 40 KB union

    const int tid  = threadIdx.x;
    const int wave = tid >> 6;
    const int lane = tid & 63;
    const int l15 = lane & 15, l4 = lane >> 4;
    const int tt   = blockIdx.x % 3;
    const int ksp  = blockIdx.x / 3;
    const int role = blockIdx.y;
    const int b    = blockIdx.z;
    const int t0   = tt * 96;
    const int icb  = ksp * 11;                     // 32-ch chunk base

    const int ld_r = lane >> 2;                    // row within 16-row issue
    const int ld_c = (((lane & 3) ^ ((lane >> 3) & 3)) << 4);  // swizzled src slot
    const int SA   = (l15 >> 1) & 3;               // read swizzle for rows i*16+l15

    const size_t xstride = (size_t)IPAD * 2;       // bytes per row (x and k)
    const char* xh_base = (const char*)xTh + ((size_t)b * TROWS + t0) * xstride;
    const char* xl_base = (const char*)xTl + ((size_t)b * TROWS + t0) * xstride;

    if (role < 2) {
        // ======================= EXC (1-term bf16) =======================
        unsigned short* xs = lds;                  // 128 rows x 32ch = 4096 sh
        unsigned short* ks = lds + 4096;           // [buf3][wave2][64x32=2048 sh]
        const int o0 = role * 128 + wave * 64;

        f32x4 acc[4][6];
#pragma unroll
        for (int i = 0; i < 4; ++i)
#pragma unroll
            for (int j = 0; j < 6; ++j) acc[i][j] = (f32x4)0.f;

        for (int c = 0; c < 11; ++c) {
            const size_t cb = (size_t)(icb + c) * 64;
            __syncthreads();                       // xs/ks reuse from prev chunk
            // x: 8 issues split across waves
            for (int j = wave; j < 8; j += 2)
                gload_lds16(xh_base + (size_t)(16 * j + ld_r) * xstride + cb + ld_c,
                            (char*)xs + j * 1024);
            // k d=0 -> buf0, d=1 -> buf1 (own wave half)
#pragma unroll
            for (int q = 0; q < 2; ++q) {
                const char* kbase = (const char*)kb2 + ((size_t)(q * OEXC) + o0) * xstride + cb;
                char* kdst = (char*)ks + (q * 2 + wave) * 4096;
#pragma unroll
                for (int j = 0; j < 4; ++j)
                    gload_lds16(kbase + (size_t)(16 * j + ld_r) * xstride + ld_c,
                                kdst + j * 1024);
            }
            asm volatile("s_waitcnt vmcnt(4)" ::: "memory");   // x + k0 landed
            __syncthreads();

            int cur = 0;
            for (int d = 0; d < DD; ++d) {
                if (d < DD - 2) {                  // prefetch k(d+2), 2 ahead
                    int nb = cur + 2; if (nb >= 3) nb -= 3;
                    const char* kbase = (const char*)kb2 +
                        ((size_t)((d + 2) * OEXC) + o0) * xstride + cb;
                    char* kdst = (char*)ks + (nb * 2 + wave) * 4096;
#pragma unroll
                    for (int j = 0; j < 4; ++j)
                        gload_lds16(kbase + (size_t)(16 * j + ld_r) * xstride + ld_c,
                                    kdst + j * 1024);
                }
                const char* kp = (const char*)ks + (cur * 2 + wave) * 4096;
                short8 A[4];
#pragma unroll
                for (int i = 0; i < 4; ++i)
                    A[i] = *(const short8*)(kp + (i * 16 + l15) * 64 + ((l4 ^ SA) << 4));
#pragma unroll
                for (int j = 0; j < 6; ++j) {
                    const int tr = j * 16 + l15 + d;
                    short8 Bv = *(const short8*)((const char*)xs + tr * 64 +
                                                 ((l4 ^ ((tr >> 1) & 3)) << 4));
#pragma unroll
                    for (int i = 0; i < 4; ++i)
                        acc[i][j] = __builtin_amdgcn_mfma_f32_16x16x32_bf16(
                            A[i], Bv, acc[i][j], 0, 0, 0);
                }
                if (d < DD - 2)
                    asm volatile("s_waitcnt vmcnt(4)" ::: "memory");  // k(d+1) landed
                else if (d == DD - 2)
                    asm volatile("s_waitcnt vmcnt(0)" ::: "memory");  // k(DD-1) landed
                cur = (cur == 2) ? 0 : cur + 1;
            }
        }
        float* dst = ksp ? pexc1 : pexc0;
#pragma unroll
        for (int i = 0; i < 4; ++i)
#pragma unroll
            for (int j = 0; j < 6; ++j) {
                const int t = t0 + j * 16 + l15;
                if (t < TOUT) {
                    float* op = dst + ((size_t)b * OEXC + o0 + i * 16 + l4 * 4) * TOUT + t;
#pragma unroll
                    for (int r = 0; r < 4; ++r) op[(size_t)r * TOUT] = acc[i][j][r];
                }
            }
    } else {
        // ============ INH (split bf16, 3-term), waves o-split ============
        unsigned short* xsh = lds;                 // 4096 sh
        unsigned short* xsl = lds + 4096;          // 4096 sh
        unsigned short* kws = lds + 8192;          // [buf3][wave2][kh 1024 | kl 1024]
        const int o0  = (role - 2) * 64;
        const int o0w = o0 + wave * 32;            // this wave's 32-o base

        f32x4 acc[2][6];
#pragma unroll
        for (int i = 0; i < 2; ++i)
#pragma unroll
            for (int j = 0; j < 6; ++j) acc[i][j] = (f32x4)0.f;

        for (int c = 0; c < 11; ++c) {
            const size_t cb = (size_t)(icb + c) * 64;
            __syncthreads();
            // x hi+lo: 16 issues split across waves (8 own)
            for (int j = wave; j < 8; j += 2) {
                gload_lds16(xh_base + (size_t)(16 * j + ld_r) * xstride + cb + ld_c,
                            (char*)xsh + j * 1024);
                gload_lds16(xl_base + (size_t)(16 * j + ld_r) * xstride + cb + ld_c,
                            (char*)xsl + j * 1024);
            }
            // k d=0 -> buf0, d=1 -> buf1: own 32 o rows, kh+kl (4 issues per d)
#pragma unroll
            for (int q = 0; q < 2; ++q) {
                const size_t ko = ((size_t)(q * OINH) + o0w) * xstride + cb;
                char* kdst = (char*)kws + (q * 2 + wave) * 4096;
#pragma unroll
                for (int j = 0; j < 2; ++j) {
                    gload_lds16((const char*)kbh + ko + (size_t)(16 * j + ld_r) * xstride + ld_c,
                                kdst + j * 1024);
                    gload_lds16((const char*)kbl + ko + (size_t)(16 * j + ld_r) * xstride + ld_c,
                                kdst + 2048 + j * 1024);
                }
            }
            asm volatile("s_waitcnt vmcnt(4)" ::: "memory");   // x + k0 landed
            __syncthreads();

            int cur = 0;
            for (int d = 0; d < DD; ++d) {
                if (d < DD - 2) {                  // prefetch k(d+2)
                    int nb = cur + 2; if (nb >= 3) nb -= 3;
                    const size_t ko = ((size_t)((d + 2) * OINH) + o0w) * xstride + cb;
                    char* kdst = (char*)kws + (nb * 2 + wave) * 4096;
#pragma unroll
                    for (int j = 0; j < 2; ++j) {
                        gload_lds16((const char*)kbh + ko + (size_t)(16 * j + ld_r) * xstride + ld_c,
                                    kdst + j * 1024);
                        gload_lds16((const char*)kbl + ko + (size_t)(16 * j + ld_r) * xstride + ld_c,
                                    kdst + 2048 + j * 1024);
                    }
                }
                const char* kp = (const char*)kws + (cur * 2 + wave) * 4096;
                short8 Ah[2], Al[2];
#pragma unroll
                for (int i = 0; i < 2; ++i) {
                    Ah[i] = *(const short8*)(kp + (i * 16 + l15) * 64 + ((l4 ^ SA) << 4));
                    Al[i] = *(const short8*)(kp + 2048 + (i * 16 + l15) * 64 + ((l4 ^ SA) << 4));
                }
#pragma unroll
                for (int j = 0; j < 6; ++j) {
                    const int tr = j * 16 + l15 + d;
                    const int xo = tr * 64 + ((l4 ^ ((tr >> 1) & 3)) << 4);
                    short8 Bh = *(const short8*)((const char*)xsh + xo);
                    short8 Bl = *(const short8*)((const char*)xsl + xo);
#pragma unroll
                    for (int i = 0; i < 2; ++i) {
                        acc[i][j] = __builtin_amdgcn_mfma_f32_16x16x32_bf16(
                            Ah[i], Bh, acc[i][j], 0, 0, 0);
                        acc[i][j] = __builtin_amdgcn_mfma_f32_16x16x32_bf16(
                            Ah[i], Bl, acc[i][j], 0, 0, 0);
                        acc[i][j] = __builtin_amdgcn_mfma_f32_16x16x32_bf16(
                            Al[i], Bh, acc[i][j], 0, 0, 0);
                    }
                }
                if (d < DD - 2)
                    asm volatile("s_waitcnt vmcnt(4)" ::: "memory");
                else if (d == DD - 2)
                    asm volatile("s_waitcnt vmcnt(0)" ::: "memory");
                cur = (cur == 2) ? 0 : cur + 1;
            }
        }
        float* dst = ksp ? pinh1 : pinh0;
#pragma unroll
        for (int i = 0; i < 2; ++i)
#pragma unroll
            for (int j = 0; j < 6; ++j) {
                const int t = t0 + j * 16 + l15;
                if (t < TOUT) {
                    float* op = dst + ((size_t)b * OINH + o0w + i * 16 + l4 * 4) * TOUT + t;
#pragma unroll
                    for (int r = 0; r < 4; ++r) op[(size_t)r * TOUT] = acc[i][j][r];
                }
            }
    }
}

// ---------------------------------------------------------------------------
// out += pexc1 (K-split reduce for exc). float4, exact grid.
// ---------------------------------------------------------------------------
__global__ void add_exc(const float* __restrict__ p1, float* __restrict__ out) {
    int n = blockIdx.x * 256 + threadIdx.x;
    float4 a = ((const float4*)out)[n];
    float4 v = ((const float4*)p1)[n];
    a.x += v.x; a.y += v.y; a.z += v.z; a.w += v.w;
    ((float4*)out)[n] = a;
}

// ---------------------------------------------------------------------------
// BN stats fused with inh K-split reduce: cinh = cinh + q1, stats over (B,T').
// ---------------------------------------------------------------------------
__global__ void bn_stats2(float* __restrict__ cinh, const float* __restrict__ q1,
                          const float* __restrict__ gamma, const float* __restrict__ beta,
                          float* __restrict__ scale, float* __restrict__ shift) {
    const int c = blockIdx.x, tid = threadIdx.x;
    float sum = 0.f, sq = 0.f;
    for (int idx = tid; idx < BB * TOUT; idx += 256) {
        int b = idx / TOUT, t = idx - b * TOUT;
        size_t off = (size_t)(b * OINH + c) * TOUT + t;
        float v = cinh[off] + q1[off];
        cinh[off] = v;
        sum += v; sq += v * v;
    }
#pragma unroll
    for (int off = 32; off; off >>= 1) {
        sum += __shfl_down(sum, off);
        sq  += __shfl_down(sq, off);
    }
    __shared__ float ls[8];
    int wid = tid >> 6;
    if ((tid & 63) == 0) { ls[wid * 2] = sum; ls[wid * 2 + 1] = sq; }
    __syncthreads();
    if (tid == 0) {
        float S = 0.f, Q = 0.f;
#pragma unroll
        for (int wv = 0; wv < 4; ++wv) { S += ls[wv * 2]; Q += ls[wv * 2 + 1]; }
        const float n = (float)(BB * TOUT);
        float mean = S / n;
        float var  = Q / n - mean * mean;
        float rs   = 1.f / sqrtf(var + 1e-5f);
        float sc   = gamma[c] * rs;
        scale[c] = sc;
        shift[c] = beta[c] - mean * sc;
    }
}

// ---------------------------------------------------------------------------
// LIF v2: LDS-tiled scan. One block per b, 128 threads (one per channel).
// Stage cinh[b] in coalesced 64-t chunks; scan from LDS (65-pad, conflict-free).
// ---------------------------------------------------------------------------
__global__ __launch_bounds__(128)
void lif2(const float* __restrict__ cinh, const float* __restrict__ scale,
          const float* __restrict__ shift, unsigned char* __restrict__ spk) {
    __shared__ float tile[128 * 65];
    const int b = blockIdx.x, c = threadIdx.x;
    const float sc = scale[c], sh = shift[c];
    const float* base = cinh + (size_t)b * OINH * TOUT;
    float v = 0.f;
    for (int tc = 0; tc < TOUT; tc += 64) {
        const int len = (TOUT - tc < 64) ? (TOUT - tc) : 64;   // 64,64,64,64,20
        const int L4 = len >> 2;
        __syncthreads();
        for (int q = c; q < 128 * L4; q += 128) {
            int cc = q / L4, e = q - cc * L4;
            float4 vv = *(const float4*)(base + (size_t)cc * TOUT + tc + e * 4);
            float* dstp = &tile[cc * 65 + e * 4];
            dstp[0] = vv.x; dstp[1] = vv.y; dstp[2] = vv.z; dstp[3] = vv.w;
        }
        __syncthreads();
        for (int t2 = 0; t2 < len; ++t2) {
            float xin = tile[c * 65 + t2] * sc + sh;
            v = 0.5f * v + xin;
            bool s = (v >= 1.f);
            spk[((size_t)(tc + t2) * BB + b) * OINH + c] = s ? 1 : 0;
            v = s ? 0.f : v;
        }
    }
}

// ---------------------------------------------------------------------------
// Round-4 fallback kernels (unchanged, known-good).
// ---------------------------------------------------------------------------
__global__ __launch_bounds__(128)
void conv_mfma(const unsigned short* __restrict__ xTh, const unsigned short* __restrict__ kb2,
               float* __restrict__ out) {
    __shared__ unsigned short xs[120 * 64];
    __shared__ unsigned short ks[2][2][64 * 64];

    const int tid  = threadIdx.x;
    const int wave = tid >> 6;
    const int lane = tid & 63;
    const int l15 = lane & 15, l4 = lane >> 4, l7 = lane & 7;
    const int b  = blockIdx.z;
    const int t0 = blockIdx.x * 96;
    const int o0 = blockIdx.y * 128 + wave * 64;

    const int ld_row = lane >> 3;
    const int ld_swz = ((l7 ^ ld_row) << 4);

    f32x4 acc[4][6];
#pragma unroll
    for (int i = 0; i < 4; ++i)
#pragma unroll
        for (int j = 0; j < 6; ++j) acc[i][j] = (f32x4)0.f;

    const char* xrow0 = (const char*)xTh + ((size_t)b * TROWS + t0) * (IPAD * 2);

    for (int ic = 0; ic < 11; ++ic) {
        const int ic0 = ic * 64;
        __syncthreads();
        for (int j = wave; j < 15; j += 2)
            gload_lds16(xrow0 + (size_t)(8 * j + ld_row) * (IPAD * 2) + ic0 * 2 + ld_swz,
                        (char*)xs + j * 1024);
        {
            const char* ksrc = (const char*)kb2 + ((size_t)o0) * (IPAD * 2) + ic0 * 2;
            char* kdst = (char*)ks + (0 * 2 + wave) * 8192;
#pragma unroll
            for (int j = 0; j < 8; ++j)
                gload_lds16(ksrc + (size_t)(8 * j + ld_row) * (IPAD * 2) + ld_swz,
                            kdst + j * 1024);
        }
        asm volatile("s_waitcnt vmcnt(0)" ::: "memory");
        __syncthreads();

        for (int d = 0; d < DD; ++d) {
            const int cur = d & 1;
            if (d < DD - 1) {
                const char* ksrc = (const char*)kb2 +
                    ((size_t)(d + 1) * OEXC + o0) * (IPAD * 2) + ic0 * 2;
                char* kdst = (char*)ks + ((cur ^ 1) * 2 + wave) * 8192;
#pragma unroll
                for (int j = 0; j < 8; ++j)
                    gload_lds16(ksrc + (size_t)(8 * j + ld_row) * (IPAD * 2) + ld_swz,
                                kdst + j * 1024);
            }
            const char* kp = (const char*)ks + (cur * 2 + wave) * 8192;
#pragma unroll
            for (int ks2 = 0; ks2 < 2; ++ks2) {
                const int cg = ks2 * 4 + l4;
                short8 A[4];
#pragma unroll
                for (int i = 0; i < 4; ++i)
                    A[i] = *(const short8*)(kp + (i * 16 + l15) * 128 + ((cg ^ l7) << 4));
#pragma unroll
                for (int j = 0; j < 6; ++j) {
                    const int tr = j * 16 + l15 + d;
                    short8 Bv = *(const short8*)((const char*)xs + tr * 128 +
                                                 ((cg ^ (tr & 7)) << 4));
#pragma unroll
                    for (int i = 0; i < 4; ++i)
                        acc[i][j] = __builtin_amdgcn_mfma_f32_16x16x32_bf16(
                            A[i], Bv, acc[i][j], 0, 0, 0);
                }
            }
            asm volatile("s_waitcnt vmcnt(0)" ::: "memory");
        }
    }

#pragma unroll
    for (int i = 0; i < 4; ++i)
#pragma unroll
        for (int j = 0; j < 6; ++j) {
            const int tt = t0 + j * 16 + l15;
            if (tt < TOUT) {
                float* op = out + ((size_t)b * OEXC + o0 + i * 16 + l4 * 4) * TOUT + tt;
#pragma unroll
                for (int r = 0; r < 4; ++r) op[(size_t)r * TOUT] = acc[i][j][r];
            }
        }
}

__global__ __launch_bounds__(128)
void conv_mfma_inh(const unsigned short* __restrict__ xTh, const unsigned short* __restrict__ xTl,
                   const unsigned short* __restrict__ kbh, const unsigned short* __restrict__ kbl,
                   float* __restrict__ cinh) {
    __shared__ unsigned short xsh[120 * 64];
    __shared__ unsigned short xsl[120 * 64];
    __shared__ unsigned short ksh[2][64 * 64];
    __shared__ unsigned short ksl[2][64 * 64];

    const int tid  = threadIdx.x;
    const int wave = tid >> 6;
    const int lane = tid & 63;
    const int l15 = lane & 15, l4 = lane >> 4, l7 = lane & 7;
    const int b  = blockIdx.z;
    const int t0 = blockIdx.x * 96;
    const int o0 = blockIdx.y * 64;
    const int wtb = wave * 48;

    const int ld_row = lane >> 3;
    const int ld_swz = ((l7 ^ ld_row) << 4);

    f32x4 acc[4][3];
#pragma unroll
    for (int i = 0; i < 4; ++i)
#pragma unroll
        for (int j = 0; j < 3; ++j) acc[i][j] = (f32x4)0.f;

    const char* xrh = (const char*)xTh + ((size_t)b * TROWS + t0) * (IPAD * 2);
    const char* xrl = (const char*)xTl + ((size_t)b * TROWS + t0) * (IPAD * 2);
    const unsigned short* kb = wave ? kbl : kbh;

    for (int ic = 0; ic < 11; ++ic) {
        const int ic0 = ic * 64;
        __syncthreads();
        for (int j = wave; j < 15; j += 2) {
            gload_lds16(xrh + (size_t)(8 * j + ld_row) * (IPAD * 2) + ic0 * 2 + ld_swz,
                        (char*)xsh + j * 1024);
            gload_lds16(xrl + (size_t)(8 * j + ld_row) * (IPAD * 2) + ic0 * 2 + ld_swz,
                        (char*)xsl + j * 1024);
        }
        {
            char* kd = wave ? (char*)ksl[0] : (char*)ksh[0];
#pragma unroll
            for (int j = 0; j < 8; ++j)
                gload_lds16((const char*)kb +
                                ((size_t)(0 * OINH + o0 + 8 * j + ld_row)) * (IPAD * 2) +
                                ic0 * 2 + ld_swz,
                            kd + j * 1024);
        }
        asm volatile("s_waitcnt vmcnt(0)" ::: "memory");
        __syncthreads();

        for (int d = 0; d < DD; ++d) {
            const int cur = d & 1;
            if (d < DD - 1) {
                char* kd = wave ? (char*)ksl[cur ^ 1] : (char*)ksh[cur ^ 1];
#pragma unroll
                for (int j = 0; j < 8; ++j)
                    gload_lds16((const char*)kb +
                                    ((size_t)((d + 1) * OINH + o0 + 8 * j + ld_row)) * (IPAD * 2) +
                                    ic0 * 2 + ld_swz,
                                kd + j * 1024);
            }
            const char* kph = (const char*)ksh[cur];
            const char* kpl = (const char*)ksl[cur];
#pragma unroll
            for (int k2 = 0; k2 < 2; ++k2) {
                const int cg = k2 * 4 + l4;
                short8 Ah[4], Al[4];
#pragma unroll
                for (int i = 0; i < 4; ++i) {
                    Ah[i] = *(const short8*)(kph + (i * 16 + l15) * 128 + ((cg ^ l7) << 4));
                    Al[i] = *(const short8*)(kpl + (i * 16 + l15) * 128 + ((cg ^ l7) << 4));
                }
#pragma unroll
                for (int j = 0; j < 3; ++j) {
                    const int tr = wtb + j * 16 + l15 + d;
                    short8 Bh = *(const short8*)((const char*)xsh + tr * 128 +
                                                 ((cg ^ (tr & 7)) << 4));
                    short8 Bl = *(const short8*)((const char*)xsl + tr * 128 +
                                                 ((cg ^ (tr & 7)) << 4));
#pragma unroll
                    for (int i = 0; i < 4; ++i) {
                        acc[i][j] = __builtin_amdgcn_mfma_f32_16x16x32_bf16(
                            Ah[i], Bh, acc[i][j], 0, 0, 0);
                        acc[i][j] = __builtin_amdgcn_mfma_f32_16x16x32_bf16(
                            Ah[i], Bl, acc[i][j], 0, 0, 0);
                        acc[i][j] = __builtin_amdgcn_mfma_f32_16x16x32_bf16(
                            Al[i], Bh, acc[i][j], 0, 0, 0);
                    }
                }
            }
            asm volatile("s_waitcnt vmcnt(0)" ::: "memory");
            __syncthreads();
        }
    }

#pragma unroll
    for (int i = 0; i < 4; ++i)
#pragma unroll
        for (int j = 0; j < 3; ++j) {
            const int tt = t0 + wtb + j * 16 + l15;
            if (tt < TOUT) {
                float* op = cinh + ((size_t)b * OINH + o0 + i * 16 + l4 * 4) * TOUT + tt;
#pragma unroll
                for (int r = 0; r < 4; ++r) op[(size_t)r * TOUT] = acc[i][j][r];
            }
        }
}

__global__ void bn_stats(const float* __restrict__ cinh, const float* __restrict__ gamma,
                         const float* __restrict__ beta, float* __restrict__ scale,
                         float* __restrict__ shift) {
    const int c = blockIdx.x, tid = threadIdx.x;
    float sum = 0.f, sq = 0.f;
    for (int idx = tid; idx < BB * TOUT; idx += 256) {
        int b = idx / TOUT, t = idx - b * TOUT;
        float v = cinh[(size_t)(b * OINH + c) * TOUT + t];
        sum += v; sq += v * v;
    }
#pragma unroll
    for (int off = 32; off; off >>= 1) {
        sum += __shfl_down(sum, off);
        sq  += __shfl_down(sq, off);
    }
    __shared__ float ls[8];
    int wid = tid >> 6;
    if ((tid & 63) == 0) { ls[wid * 2] = sum; ls[wid * 2 + 1] = sq; }
    __syncthreads();
    if (tid == 0) {
        float S = 0.f, Q = 0.f;
#pragma unroll
        for (int wv = 0; wv < 4; ++wv) { S += ls[wv * 2]; Q += ls[wv * 2 + 1]; }
        const float n = (float)(BB * TOUT);
        float mean = S / n;
        float var  = Q / n - mean * mean;
        float rs   = 1.f / sqrtf(var + 1e-5f);
        float sc   = gamma[c] * rs;
        scale[c] = sc;
        shift[c] = beta[c] - mean * sc;
    }
}

__global__ __launch_bounds__(256)
void finale(const unsigned char* __restrict__ spk, const float* __restrict__ wt,
            float* __restrict__ out) {
    __shared__ float s_lds[64 * 129];
    const int tid = threadIdx.x;
    const int tx = tid & 15, ty = tid >> 4;
    const int b = blockIdx.z, t0 = blockIdx.x * 64, o0 = blockIdx.y * 64;

#pragma unroll
    for (int s = 0; s < 32; ++s) {
        int f = tid + s * 256;
        int tt = f >> 7, c = f & 127;
        float v = 0.f;
        if (t0 + tt < TOUT) v = (float)spk[((size_t)(t0 + tt) * BB + b) * OINH + c];
        s_lds[tt * 129 + c] = v;
    }
    __syncthreads();

    float acc[4][4] = {{0.f}};
#pragma unroll 4
    for (int c = 0; c < 128; ++c) {
        float4 wv = *(const float4*)(wt + c * OEXC + o0 + ty * 4);
        float wvv[4] = {wv.x, wv.y, wv.z, wv.w};
        float sv[4];
#pragma unroll
        for (int rt = 0; rt < 4; ++rt) sv[rt] = s_lds[(tx * 4 + rt) * 129 + c];
#pragma unroll
        for (int ro = 0; ro < 4; ++ro)
#pragma unroll
            for (int rt = 0; rt < 4; ++rt)
                acc[ro][rt] += wvv[ro] * sv[rt];
    }

    const int tvalid = TOUT - t0;
    if (tx * 4 < tvalid) {
#pragma unroll
        for (int ro = 0; ro < 4; ++ro) {
            float* op = out + (size_t)(b * OEXC + o0 + ty * 4 + ro) * TOUT + t0 + tx * 4;
            float4 v = *(float4*)op;
            v.x += acc[ro][0]; v.y += acc[ro][1]; v.z += acc[ro][2]; v.w += acc[ro][3];
            *(float4*)op = v;
        }
    }
}

// legacy lif (fallback paths)
__global__ void lif_kernel(const float* __restrict__ cinh, const float* __restrict__ scale,
                           const float* __restrict__ shift, unsigned char* __restrict__ spk) {
    const int b = blockIdx.x, c = threadIdx.x;
    const float sc = scale[c], sh = shift[c];
    const float* row = cinh + (size_t)(b * OINH + c) * TOUT;
    float v = 0.f;
    for (int t = 0; t < TOUT; ++t) {
        float xin = row[t] * sc + sh;
        v = 0.5f * v + xin;
        unsigned char s = (v >= 1.f) ? 1 : 0;
        spk[((size_t)t * BB + b) * OINH + c] = s;
        v = (v >= 1.f) ? 0.f : v;
    }
}

// ---------------------------------------------------------------------------
extern "C" void kernel_launch(void* const* d_in, const int* in_sizes, int n_in,
                              void* d_out, int out_size, void* d_ws, size_t ws_size,
                              hipStream_t stream) {
    const float* x       = (const float*)d_in[0];
    const float* W_inh   = (const float*)d_in[1];
    const float* P_inh   = (const float*)d_in[2];
    const float* SIG_inh = (const float*)d_in[3];
    const float* W_exc   = (const float*)d_in[4];
    const float* P_exc   = (const float*)d_in[5];
    const float* SIG_exc = (const float*)d_in[6];
    const float* w_ei    = (const float*)d_in[7];
    const float* gamma   = (const float*)d_in[8];
    const float* beta    = (const float*)d_in[9];
    float* out = (float*)d_out;

    const size_t XT_ELEMS   = (size_t)BB * TROWS * IPAD;    // 14,057,472
    const size_t KEXC_ELEMS = (size_t)DD * OEXC * IPAD;     //  4,505,600
    const size_t KINH_ELEMS = (size_t)DD * OINH * IPAD;     //  2,252,800
    const size_t CINH_ELEMS = (size_t)BB * OINH * TOUT;     //  2,260,992
    const size_t PEXC_ELEMS = (size_t)BB * OEXC * TOUT;     //  4,521,984

    const size_t NEED_FAST = 2 * XT_ELEMS * 2 + KEXC_ELEMS * 2 + 2 * KINH_ELEMS * 2 +
                             CINH_ELEMS * 4 + OINH * OEXC * 4 + CINH_ELEMS;  // ~85.7 MB
    const size_t NEED_FAST2 = (2 * XT_ELEMS + KEXC_ELEMS + 2 * KINH_ELEMS) * 2 +
                              (PEXC_ELEMS + 2 * CINH_ELEMS + OINH * OEXC + 256) * 4 +
                              CINH_ELEMS;                                    // ~113 MB

    if (ws_size >= NEED_FAST2) {
        // ---- fast2: fused v3 convs (deep pipeline), K-split x2 ----
        unsigned short* xTh = (unsigned short*)d_ws;
        unsigned short* xTl = xTh + XT_ELEMS;
        unsigned short* kb2 = xTl + XT_ELEMS;
        unsigned short* kbh = kb2 + KEXC_ELEMS;
        unsigned short* kbl = kbh + KINH_ELEMS;
        float* pexc1 = (float*)(kbl + KINH_ELEMS);
        float* cinh  = pexc1 + PEXC_ELEMS;          // doubles as pinh0
        float* pinh1 = cinh + CINH_ELEMS;
        float* wt    = pinh1 + CINH_ELEMS;
        float* scale = wt + OINH * OEXC;
        float* shift = scale + OINH;
        unsigned char* spk = (unsigned char*)(shift + OINH);

        hipLaunchKernelGGL(kexc_build, dim3((OEXC * IPAD + 255) / 256), dim3(256), 0, stream,
                           W_exc, P_exc, SIG_exc, kb2);
        hipLaunchKernelGGL(kinh_build, dim3((OINH * IPAD + 255) / 256), dim3(256), 0, stream,
                           W_inh, P_inh, SIG_inh, kbh, kbl);
        hipLaunchKernelGGL(xt_kernel, dim3(5, 11, 64), dim3(256), 0, stream, x, xTh, xTl);
        hipLaunchKernelGGL(wt_kernel, dim3(128), dim3(256), 0, stream, w_ei, wt);

        hipLaunchKernelGGL(conv_fused_v3, dim3(6, 4, 64), dim3(128), 0, stream,
                           xTh, xTl, kb2, kbh, kbl, out, pexc1, cinh, pinh1);

        hipLaunchKernelGGL(add_exc, dim3((unsigned)(PEXC_ELEMS / 4 / 256)), dim3(256), 0, stream,
                           pexc1, out);
        hipLaunchKernelGGL(bn_stats2, dim3(128), dim3(256), 0, stream,
                           cinh, pinh1, gamma, beta, scale, shift);
        hipLaunchKernelGGL(lif2, dim3(64), dim3(128), 0, stream, cinh, scale, shift, spk);
        hipLaunchKernelGGL(finale, dim3(5, 4, 64), dim3(256), 0, stream, spk, wt, out);
    } else if (ws_size >= NEED_FAST) {
        // ---- round-4 fast path (known good) ----
        unsigned short* xTh = (unsigned short*)d_ws;
        unsigned short* xTl = xTh + XT_ELEMS;
        unsigned short* kb2 = xTl + XT_ELEMS;
        unsigned short* kbh = kb2 + KEXC_ELEMS;
        unsigned short* kbl = kbh + KINH_ELEMS;
        float* cinh  = (float*)(kbl + KINH_ELEMS);
        float* wt    = cinh + CINH_ELEMS;
        float* scale = wt + OINH * OEXC;
        float* shift = scale + OINH;
        unsigned char* spk = (unsigned char*)(shift + OINH);

        hipLaunchKernelGGL(kexc_build, dim3((OEXC * IPAD + 255) / 256), dim3(256), 0, stream,
                           W_exc, P_exc, SIG_exc, kb2);
        hipLaunchKernelGGL(kinh_build, dim3((OINH * IPAD + 255) / 256), dim3(256), 0, stream,
                           W_inh, P_inh, SIG_inh, kbh, kbl);
        hipLaunchKernelGGL(xt_kernel, dim3(5, 11, 64), dim3(256), 0, stream, x, xTh, xTl);
        hipLaunchKernelGGL(wt_kernel, dim3(128), dim3(256), 0, stream, w_ei, wt);

        hipLaunchKernelGGL(conv_mfma, dim3(3, 2, 64), dim3(128), 0, stream, xTh, kb2, out);
        hipLaunchKernelGGL(conv_mfma_inh, dim3(3, 2, 64), dim3(128), 0, stream,
                           xTh, xTl, kbh, kbl, cinh);

        hipLaunchKernelGGL(bn_stats, dim3(128), dim3(256), 0, stream, cinh, gamma, beta, scale, shift);
        hipLaunchKernelGGL(lif_kernel, dim3(64), dim3(128), 0, stream, cinh, scale, shift, spk);
        hipLaunchKernelGGL(finale, dim3(5, 4, 64), dim3(256), 0, stream, spk, wt, out);
    } else {
        // ---- minimal fallback: exc MFMA + inh via round-4 structures won't fit;
        //      reuse round-4 path pieces with hi-only xT (round-3 config) ----
        unsigned short* xTh = (unsigned short*)d_ws;
        unsigned short* kb2 = xTh + XT_ELEMS;
        float* kt_inh = (float*)(kb2 + KEXC_ELEMS);
        float* cinh   = kt_inh + 2240000;
        float* wt     = cinh + CINH_ELEMS;
        float* scale  = wt + OINH * OEXC;
        float* shift  = scale + OINH;
        unsigned char* spk = (unsigned char*)(shift + OINH);

        hipLaunchKernelGGL(kexc_build, dim3((OEXC * IPAD + 255) / 256), dim3(256), 0, stream,
                           W_exc, P_exc, SIG_exc, kb2);
        hipLaunchKernelGGL(build_kt, dim3(350), dim3(256), 0, stream,
                           W_inh, P_inh, SIG_inh, kt_inh, OINH);
        hipLaunchKernelGGL(xt_kernel, dim3(5, 11, 64), dim3(256), 0, stream, x, xTh,
                           (unsigned short*)nullptr);
        hipLaunchKernelGGL(wt_kernel, dim3(128), dim3(256), 0, stream, w_ei, wt);

        hipLaunchKernelGGL(conv_mfma, dim3(3, 2, 64), dim3(128), 0, stream, xTh, kb2, out);
        // fp32 inh conv fallback
        // (conv_dcls retained in round-3 form would be needed here; reuse MFMA-free path)
        // For safety this path uses the fp32 kernel below.
        extern __global__ void conv_dcls_fb(const float*, const float*, float*, int);
        hipLaunchKernelGGL(conv_dcls_fb, dim3(5, 1, 64), dim3(256), 0, stream, x, kt_inh, cinh, OINH);

        hipLaunchKernelGGL(bn_stats, dim3(128), dim3(256), 0, stream, cinh, gamma, beta, scale, shift);
        hipLaunchKernelGGL(lif_kernel, dim3(64), dim3(128), 0, stream, cinh, scale, shift, spk);
        hipLaunchKernelGGL(finale, dim3(5, 4, 64), dim3(256), 0, stream, spk, wt, out);
    }
}

// fp32 inh conv fallback definition (round-2 kernel)
__global__ __launch_bounds__(256)
void conv_dcls_fb(const float* __restrict__ x, const float* __restrict__ kt,
                  float* __restrict__ out, int O) {
    __shared__ float k_lds[100 * 128];
    __shared__ float x_lds[4 * 88];

    const int tid = threadIdx.x;
    const int tx = tid & 7;
    const int ty = tid >> 3;
    const int b  = blockIdx.z;
    const int t0 = blockIdx.x * 64;
    const int o0 = blockIdx.y * 128;
    const int tlim = TIN - t0;

    float acc[4][8];
#pragma unroll
    for (int ro = 0; ro < 4; ++ro)
#pragma unroll
        for (int rt = 0; rt < 8; ++rt) acc[ro][rt] = 0.f;

    for (int chunk = 0; chunk < 175; ++chunk) {
        const int i0 = chunk * 4;
        __syncthreads();
#pragma unroll
        for (int s = 0; s < 13; ++s) {
            int f = tid + s * 256;
            if (f < 3200) {
                int j = f >> 5, o4 = f & 31;
                ((float4*)k_lds)[f] =
                    *(const float4*)(kt + (size_t)(i0 * DD + j) * O + o0 + o4 * 4);
            }
        }
        if (tid < 88) {
            int icc = tid / 22, wq = tid % 22;
            float4 v = make_float4(0.f, 0.f, 0.f, 0.f);
            if (wq * 4 < tlim)
                v = *(const float4*)(x + (size_t)(b * CI + i0 + icc) * TIN + t0 + wq * 4);
            ((float4*)x_lds)[tid] = v;
        }
        __syncthreads();
#pragma unroll
        for (int icc = 0; icc < 4; ++icc) {
            float xv[32];
#pragma unroll
            for (int wq = 0; wq < 8; ++wq)
                *(float4*)(xv + 4 * wq) = ((const float4*)(x_lds + icc * 88))[tx * 2 + wq];
#pragma unroll
            for (int d = 0; d < DD; ++d) {
                float4 kv = ((const float4*)(k_lds + (icc * DD + d) * 128))[ty];
                float kvv[4] = {kv.x, kv.y, kv.z, kv.w};
#pragma unroll
                for (int ro = 0; ro < 4; ++ro)
#pragma unroll
                    for (int rt = 0; rt < 8; ++rt)
                        acc[ro][rt] += kvv[ro] * xv[rt + d];
            }
        }
    }
    const int tvalid = TOUT - t0;
#pragma unroll
    for (int ro = 0; ro < 4; ++ro) {
        float* op = out + (size_t)(b * O + o0 + ty * 4 + ro) * TOUT + t0;
#pragma unroll
        for (int u = 0; u < 2; ++u) {
            int toff = tx * 8 + u * 4;
            if (toff < tvalid) {
                float4 v = make_float4(acc[ro][u * 4 + 0], acc[ro][u * 4 + 1],
                                       acc[ro][u * 4 + 2], acc[ro][u * 4 + 3]);
                *(float4*)(op + toff) = v;
            }
        }
    }
}